// Round 11
// baseline (224.856 us; speedup 1.0000x reference)
//
#include <hip/hip_runtime.h>
#include <hip/hip_bf16.h>
#include <math.h>

typedef __bf16 bf16;
typedef __bf16 bf16x4 __attribute__((ext_vector_type(4)));
typedef __bf16 bf16x8 __attribute__((ext_vector_type(8)));
typedef float f32x4 __attribute__((ext_vector_type(4)));

#define BB  128
#define TT  64
#define BTT 8192
#define HH  512
#define EE  1024
#define KA  49
#define NV  10000

__device__ __forceinline__ float ftanh(float x) {
    float cx = fminf(fmaxf(x, -15.f), 15.f);
    float e = __expf(2.f * cx);
    return (e - 1.f) * __builtin_amdgcn_rcpf(e + 1.f);
}
__device__ __forceinline__ float fsigmoid(float x) {
    return __builtin_amdgcn_rcpf(1.f + __expf(-x));
}

// ---------------- fused converts (one pass, float4 -> bf16x4) ----------------
__device__ __forceinline__ void cvt4(const float* __restrict__ s, bf16* __restrict__ d) {
    f32x4 v = *(const f32x4*)s;
    bf16x4 o = { (bf16)v[0], (bf16)v[1], (bf16)v[2], (bf16)v[3] };
    *(bf16x4*)d = o;
}
__device__ __forceinline__ void cvt4nt(const float* __restrict__ s, bf16* __restrict__ d) {
    f32x4 v = __builtin_nontemporal_load((const f32x4*)s);
    bf16x4 o = { (bf16)v[0], (bf16)v[1], (bf16)v[2], (bf16)v[3] };
    *(bf16x4*)d = o;
}

// x pass removed entirely (gate stages x f32 directly). Wm handled by gate_mid filler.
__global__ __launch_bounds__(256)
void prep_kernel(const float* __restrict__ hid,
                 const float* __restrict__ V, const float* __restrict__ Wv,
                 const float* __restrict__ Wg, const float* __restrict__ Ws,
                 const float* __restrict__ Wx, const float* __restrict__ Wsh,
                 bf16* __restrict__ hb,
                 bf16* __restrict__ Vb, bf16* __restrict__ Wvb, bf16* __restrict__ Wgb,
                 bf16* __restrict__ Wsb, bf16* __restrict__ Wxb, bf16* __restrict__ Wshb,
                 bf16* __restrict__ zbuf)
{
    if (blockIdx.x == 0 && threadIdx.x < 128) {
        bf16x8 z = {};
        *(bf16x8*)(zbuf + threadIdx.x * 8) = z;
    }

    const long NH = (long)BTT * HH;
    const long NVV = (long)BB * KA * HH;
    const long NWX = (long)HH * EE;
    const long NWSH = (long)HH * HH;
    const long NW = (long)KA * HH;
    const long total4 = (NH + NVV + NWX + NWSH + 3 * NW) >> 2;

    long t0 = (long)blockIdx.x * 256 + threadIdx.x;
    long st = (long)gridDim.x * 256;
    for (long i4 = t0; i4 < total4; i4 += st) {
        long i = i4 << 2;
        if (i < NH) { cvt4(hid + i, hb + i); continue; }
        i -= NH;
        if (i < NVV) { cvt4nt(V + i, Vb + i); continue; }
        i -= NVV;
        if (i < NWX) { cvt4nt(Wx + i, Wxb + i); continue; }
        i -= NWX;
        if (i < NWSH) { cvt4nt(Wsh + i, Wshb + i); continue; }
        i -= NWSH;
        if (i < NW) { cvt4nt(Wv + i, Wvb + i); continue; }
        i -= NW;
        if (i < NW) { cvt4nt(Wg + i, Wgb + i); continue; }
        i -= NW;
        cvt4nt(Ws + i, Wsb + i);
    }
}

// ---------------- pipelined 128x128 GEMM core (ring-4 BK=32, lookahead-3, counted vmcnt) ----
template<int EPI, bool SHIFT>
__device__ __forceinline__ void gemm128_core(
    bf16* smem,
    const bf16* __restrict__ A1, const bf16* __restrict__ B1, int K1,
    const bf16* __restrict__ A2, const bf16* __restrict__ B2, int K2,
    int N, const float* __restrict__ eaux, void* __restrict__ outv, int ldo,
    int bm0, int bn0, const bf16* __restrict__ zbuf)
{
    const int tid = threadIdx.x;
    const int lane = tid & 63;
    const int wid = tid >> 6;
    const int wm = (wid >> 1) * 64;
    const int wn = (wid & 1) * 64;
    const int rA = lane & 15;
    const int ks = lane >> 4;
    const int swzB = (ks ^ ((rA >> 1) & 3)) * 16;

    const int c0 = tid, c1 = tid + 256;
    const int row0 = c0 >> 2, row1 = c1 >> 2;
    const int gc0 = ((c0 & 3) ^ ((row0 >> 1) & 3)) * 8;
    const int gc1 = ((c1 & 3) ^ ((row1 >> 1) & 3)) * 8;
    const int br0 = (bn0 + row0 < N) ? bn0 + row0 : N - 1;
    const int br1 = (bn0 + row1 < N) ? bn0 + row1 : N - 1;

    const int NT1 = K1 >> 5;
    const int NT2 = K2 >> 5;
    const int NT = NT1 + NT2;

    const bf16* A1r0 = A1 + (size_t)(bm0 + row0) * K1 + gc0;
    const bf16* A1r1 = A1 + (size_t)(bm0 + row1) * K1 + gc1;
    const bf16* B1r0 = B1 + (size_t)br0 * K1 + gc0;
    const bf16* B1r1 = B1 + (size_t)br1 * K1 + gc1;
    const bf16 *A2r0 = nullptr, *A2r1 = nullptr, *B2r0 = nullptr, *B2r1 = nullptr;
    if (K2 > 0) {
        if (SHIFT) {
            A2r0 = (((bm0 + row0) & 63) == 0) ? zbuf + gc0
                                              : A2 + (size_t)(bm0 + row0 - 1) * K2 + gc0;
            A2r1 = (((bm0 + row1) & 63) == 0) ? zbuf + gc1
                                              : A2 + (size_t)(bm0 + row1 - 1) * K2 + gc1;
        } else {
            A2r0 = A2 + (size_t)(bm0 + row0) * K2 + gc0;
            A2r1 = A2 + (size_t)(bm0 + row1) * K2 + gc1;
        }
        B2r0 = B2 + (size_t)br0 * K2 + gc0;
        B2r1 = B2 + (size_t)br1 * K2 + gc1;
    }

    auto stage = [&](int t) {
        const bf16 *a0, *a1, *b0, *b1; int k0;
        if (t < NT1) { k0 = t << 5;          a0 = A1r0; a1 = A1r1; b0 = B1r0; b1 = B1r1; }
        else         { k0 = (t - NT1) << 5;  a0 = A2r0; a1 = A2r1; b0 = B2r0; b1 = B2r1; }
        char* base = (char*)smem + (t & 3) * 16384;
        __builtin_amdgcn_global_load_lds(
            (const __attribute__((address_space(1))) unsigned int*)(a0 + k0),
            (__attribute__((address_space(3))) unsigned int*)(base + c0 * 16), 16, 0, 0);
        __builtin_amdgcn_global_load_lds(
            (const __attribute__((address_space(1))) unsigned int*)(a1 + k0),
            (__attribute__((address_space(3))) unsigned int*)(base + c1 * 16), 16, 0, 0);
        __builtin_amdgcn_global_load_lds(
            (const __attribute__((address_space(1))) unsigned int*)(b0 + k0),
            (__attribute__((address_space(3))) unsigned int*)(base + 8192 + c0 * 16), 16, 0, 0);
        __builtin_amdgcn_global_load_lds(
            (const __attribute__((address_space(1))) unsigned int*)(b1 + k0),
            (__attribute__((address_space(3))) unsigned int*)(base + 8192 + c1 * 16), 16, 0, 0);
    };

    f32x4 acc[4][4] = {};

    stage(0); stage(1); stage(2);
    asm volatile("s_waitcnt vmcnt(8)" ::: "memory");
    __builtin_amdgcn_s_barrier();

    for (int t = 0; t < NT; ++t) {
        const char* sA = (const char*)smem + (t & 3) * 16384;
        const char* sB = sA + 8192;

        bf16x8 af[4], bfr[4];
        #pragma unroll
        for (int mi = 0; mi < 4; ++mi)
            af[mi] = *(const bf16x8*)(sA + (wm + mi * 16 + rA) * 64 + swzB);
        #pragma unroll
        for (int ni = 0; ni < 4; ++ni)
            bfr[ni] = *(const bf16x8*)(sB + (wn + ni * 16 + rA) * 64 + swzB);

        if (t + 3 < NT) {
            stage(t + 3);
            asm volatile("s_waitcnt vmcnt(8)" ::: "memory");
        } else if (t + 2 < NT) {
            asm volatile("s_waitcnt vmcnt(4)" ::: "memory");
        } else {
            asm volatile("s_waitcnt vmcnt(0)" ::: "memory");
        }
        __builtin_amdgcn_s_barrier();

        __builtin_amdgcn_s_setprio(1);
        #pragma unroll
        for (int mi = 0; mi < 4; ++mi) {
            #pragma unroll
            for (int ni = 0; ni < 4; ++ni)
                acc[mi][ni] = __builtin_amdgcn_mfma_f32_16x16x32_bf16(af[mi], bfr[ni], acc[mi][ni], 0, 0, 0);
        }
        __builtin_amdgcn_s_setprio(0);
        __builtin_amdgcn_s_barrier();
    }

    #pragma unroll
    for (int mi = 0; mi < 4; ++mi) {
        #pragma unroll
        for (int ni = 0; ni < 4; ++ni) {
            const int col = bn0 + wn + ni * 16 + rA;
            if (col < N) {
                #pragma unroll
                for (int r = 0; r < 4; ++r) {
                    const int rowg = bm0 + wm + mi * 16 + ks * 4 + r;
                    float v = acc[mi][ni][r];
                    if (EPI == 0) {
                        ((bf16*)outv)[(size_t)rowg * ldo + col] =
                            (bf16)(fsigmoid(v) * ftanh(eaux[(size_t)rowg * ldo + col]));
                    } else {
                        ((float*)outv)[(size_t)rowg * ldo + col] = v;
                    }
                }
            }
        }
    }
}

// ---------------- gate with direct-f32 x staging (no xb conversion pass) ----------------
__device__ __forceinline__ void gate128f(
    char* smem, const float* __restrict__ xf, const bf16* __restrict__ Wxb,
    const bf16* __restrict__ hb, const bf16* __restrict__ Wshb,
    const float* __restrict__ cel, bf16* __restrict__ sentb,
    int bm0, int bn0, const bf16* __restrict__ zbuf)
{
    const int NT1 = EE >> 5;
    const int NT = NT1 + (HH >> 5);

    const int tid = threadIdx.x;
    const int lane = tid & 63;
    const int wid = tid >> 6;
    const int wm = (wid >> 1) * 64;
    const int wn = (wid & 1) * 64;
    const int rA = lane & 15;
    const int ks = lane >> 4;
    const int swzB = (ks ^ ((rA >> 1) & 3)) * 16;

    const float* xsrc[4];
    #pragma unroll
    for (int j = 0; j < 4; ++j) {
        const int c = tid + 256 * j;
        const int row = c >> 3, slot = c & 7;
        xsrc[j] = xf + (size_t)(bm0 + row) * EE + ((slot ^ ((row >> 1) & 7)) << 2);
    }
    const int cb0 = tid, cb1 = tid + 256;
    const int brow0 = cb0 >> 2, brow1 = cb1 >> 2;
    const int gb0 = ((cb0 & 3) ^ ((brow0 >> 1) & 3)) * 8;
    const int gb1 = ((cb1 & 3) ^ ((brow1 >> 1) & 3)) * 8;

    const bf16* B1r0 = Wxb + (size_t)(bn0 + brow0) * EE + gb0;
    const bf16* B1r1 = Wxb + (size_t)(bn0 + brow1) * EE + gb1;
    const bf16* B2r0 = Wshb + (size_t)(bn0 + brow0) * HH + gb0;
    const bf16* B2r1 = Wshb + (size_t)(bn0 + brow1) * HH + gb1;
    const bf16* A2r0 = (((bm0 + brow0) & 63) == 0) ? zbuf + gb0
                                                   : hb + (size_t)(bm0 + brow0 - 1) * HH + gb0;
    const bf16* A2r1 = (((bm0 + brow1) & 63) == 0) ? zbuf + gb1
                                                   : hb + (size_t)(bm0 + brow1 - 1) * HH + gb1;

    auto stage = [&](int t, int slot) {
        char* base = smem + slot * 24576;
        if (t < NT1) {
            const int k0 = t << 5;
            #pragma unroll
            for (int j = 0; j < 4; ++j)
                __builtin_amdgcn_global_load_lds(
                    (const __attribute__((address_space(1))) unsigned int*)(xsrc[j] + k0),
                    (__attribute__((address_space(3))) unsigned int*)(base + (tid + 256 * j) * 16), 16, 0, 0);
            __builtin_amdgcn_global_load_lds(
                (const __attribute__((address_space(1))) unsigned int*)(B1r0 + k0),
                (__attribute__((address_space(3))) unsigned int*)(base + 16384 + cb0 * 16), 16, 0, 0);
            __builtin_amdgcn_global_load_lds(
                (const __attribute__((address_space(1))) unsigned int*)(B1r1 + k0),
                (__attribute__((address_space(3))) unsigned int*)(base + 16384 + cb1 * 16), 16, 0, 0);
        } else {
            const int k0 = (t - NT1) << 5;
            __builtin_amdgcn_global_load_lds(
                (const __attribute__((address_space(1))) unsigned int*)(A2r0 + k0),
                (__attribute__((address_space(3))) unsigned int*)(base + cb0 * 16), 16, 0, 0);
            __builtin_amdgcn_global_load_lds(
                (const __attribute__((address_space(1))) unsigned int*)(A2r1 + k0),
                (__attribute__((address_space(3))) unsigned int*)(base + cb1 * 16), 16, 0, 0);
            __builtin_amdgcn_global_load_lds(
                (const __attribute__((address_space(1))) unsigned int*)(B2r0 + k0),
                (__attribute__((address_space(3))) unsigned int*)(base + 16384 + cb0 * 16), 16, 0, 0);
            __builtin_amdgcn_global_load_lds(
                (const __attribute__((address_space(1))) unsigned int*)(B2r1 + k0),
                (__attribute__((address_space(3))) unsigned int*)(base + 16384 + cb1 * 16), 16, 0, 0);
        }
    };

    f32x4 acc[4][4] = {};

    stage(0, 0); stage(1, 1);
    asm volatile("s_waitcnt vmcnt(6)" ::: "memory");
    __builtin_amdgcn_s_barrier();

    int slR = 0, slS = 2;
    for (int t = 0; t < NT; ++t) {
        const char* base = smem + slR * 24576;
        const char* sB = base + 16384;

        bf16x8 af[4], bfr[4];
        if (t < NT1) {
            #pragma unroll
            for (int mi = 0; mi < 4; ++mi) {
                const int row = wm + mi * 16 + rA;
                const int m = (row >> 1) & 7;
                f32x4 lo = *(const f32x4*)(base + row * 128 + (((2 * ks) ^ m) << 4));
                f32x4 hi = *(const f32x4*)(base + row * 128 + (((2 * ks + 1) ^ m) << 4));
                bf16x8 v = { (bf16)lo[0], (bf16)lo[1], (bf16)lo[2], (bf16)lo[3],
                             (bf16)hi[0], (bf16)hi[1], (bf16)hi[2], (bf16)hi[3] };
                af[mi] = v;
            }
        } else {
            #pragma unroll
            for (int mi = 0; mi < 4; ++mi)
                af[mi] = *(const bf16x8*)(base + (wm + mi * 16 + rA) * 64 + swzB);
        }
        #pragma unroll
        for (int ni = 0; ni < 4; ++ni)
            bfr[ni] = *(const bf16x8*)(sB + (wn + ni * 16 + rA) * 64 + swzB);

        if (t + 2 < NT) {
            stage(t + 2, slS);
            if (t + 2 < NT1) asm volatile("s_waitcnt vmcnt(6)" ::: "memory");
            else             asm volatile("s_waitcnt vmcnt(4)" ::: "memory");
        } else {
            asm volatile("s_waitcnt vmcnt(0)" ::: "memory");
        }
        __builtin_amdgcn_s_barrier();

        __builtin_amdgcn_s_setprio(1);
        #pragma unroll
        for (int mi = 0; mi < 4; ++mi) {
            #pragma unroll
            for (int ni = 0; ni < 4; ++ni)
                acc[mi][ni] = __builtin_amdgcn_mfma_f32_16x16x32_bf16(af[mi], bfr[ni], acc[mi][ni], 0, 0, 0);
        }
        __builtin_amdgcn_s_setprio(0);
        __builtin_amdgcn_s_barrier();

        slR = (slR == 2) ? 0 : slR + 1;
        slS = (slS == 2) ? 0 : slS + 1;
    }

    #pragma unroll
    for (int mi = 0; mi < 4; ++mi) {
        #pragma unroll
        for (int ni = 0; ni < 4; ++ni) {
            const int col = bn0 + wn + ni * 16 + rA;
            #pragma unroll
            for (int r = 0; r < 4; ++r) {
                const int rowg = bm0 + wm + mi * 16 + ks * 4 + r;
                sentb[(size_t)rowg * HH + col] =
                    (bf16)(fsigmoid(acc[mi][ni][r]) * ftanh(cel[(size_t)rowg * HH + col]));
            }
        }
    }
}

// merged launch: gate (256) + cv (49) + cg (64) + Wm-convert filler (143) = 512 blocks.
__global__ __launch_bounds__(256, 2)
void gate_mid128(const float* __restrict__ xf, const bf16* __restrict__ Wxb,
                 const bf16* __restrict__ Wshb,
                 const float* __restrict__ cel, bf16* __restrict__ sentb,
                 const bf16* __restrict__ Vb, const bf16* __restrict__ Wvb,
                 const bf16* __restrict__ hb, const bf16* __restrict__ Wgb,
                 float* __restrict__ cv, float* __restrict__ cg,
                 const float* __restrict__ Wm, bf16* __restrict__ Wmb,
                 const bf16* __restrict__ zbuf)
{
    __shared__ char smem[73728];
    const int bid = blockIdx.x;
    if (bid >= 369) {
        const long n4 = ((long)NV * HH) >> 2;
        for (long i4 = (long)(bid - 369) * 256 + threadIdx.x; i4 < n4; i4 += 143L * 256)
            cvt4nt(Wm + (i4 << 2), Wmb + (i4 << 2));
        return;
    }
    if (bid < 256) {
        const int lin = (bid & 7) * 32 + (bid >> 3);
        gate128f(smem, xf, Wxb, hb, Wshb, cel, sentb,
                 (lin >> 2) * 128, (lin & 3) * 128, zbuf);
    } else if (bid < 305) {
        gemm128_core<2, false>((bf16*)smem, Vb, Wvb, HH, nullptr, nullptr, 0, KA, nullptr,
                               (void*)cv, KA, (bid - 256) * 128, 0, nullptr);
    } else {
        gemm128_core<2, false>((bf16*)smem, hb, Wgb, HH, nullptr, nullptr, 0, KA, nullptr,
                               (void*)cg, KA, (bid - 305) * 128, 0, nullptr);
    }
}

// ---------------- cs_z: cs64 (128 blocks) + z-precompute (2048 blocks) in one launch ------
__global__ __launch_bounds__(256, 2)
void cs_z(const bf16* __restrict__ sentb, const bf16* __restrict__ Wsb,
          float* __restrict__ cs,
          const float* __restrict__ cv, const float* __restrict__ cg,
          const float* __restrict__ wh, float* __restrict__ zb)
{
    __shared__ char sm[32768];
    const int bid = blockIdx.x;
    const int tid = threadIdx.x;

    if (bid >= 128) {
        float* cvL = (float*)sm;
        float* whL = (float*)(sm + 9604);
        float* cgL = (float*)(sm + 9860);
        const int w = tid >> 6, lane = tid & 63;
        const int bt0 = (bid - 128) * 4;
        const int b = bt0 >> 6;
        const int bt = bt0 + w;

        const float* cvb = cv + (size_t)b * KA * KA;
        for (int i = tid; i < KA * KA; i += 256) cvL[i] = cvb[i];
        if (tid < KA) whL[tid] = wh[tid];
        if (lane < KA) cgL[w * KA + lane] = cg[(size_t)bt * KA + lane];
        __syncthreads();

        if (lane < KA) {
            const float* cvk = cvL + lane * KA;
            const float* cgr = cgL + w * KA;
            float acc = 0.f;
            #pragma unroll 7
            for (int n = 0; n < KA; ++n)
                acc += ftanh(cvk[n] + cgr[n]) * whL[n];
            zb[(size_t)bt * KA + lane] = acc;
        }
        return;
    }

    bf16* smem = (bf16*)sm;
    const int bm0 = bid * 64;
    const int lane = tid & 63;
    const int w = tid >> 6;
    const int rA = lane & 15;
    const int ks = lane >> 4;
    const int swzB = (ks ^ ((rA >> 1) & 3)) * 16;

    const int row = tid >> 2;
    const int gc = ((tid & 3) ^ ((row >> 1) & 3)) * 8;
    const int browc = (row < KA) ? row : KA - 1;
    const bf16* Ar = sentb + (size_t)(bm0 + row) * HH + gc;
    const bf16* Br = Wsb + (size_t)browc * HH + gc;

    auto stage = [&](int t) {
        char* base = (char*)smem + (t & 3) * 8192;
        const int k0 = t << 5;
        __builtin_amdgcn_global_load_lds(
            (const __attribute__((address_space(1))) unsigned int*)(Ar + k0),
            (__attribute__((address_space(3))) unsigned int*)(base + tid * 16), 16, 0, 0);
        __builtin_amdgcn_global_load_lds(
            (const __attribute__((address_space(1))) unsigned int*)(Br + k0),
            (__attribute__((address_space(3))) unsigned int*)(base + 4096 + tid * 16), 16, 0, 0);
    };

    f32x4 acc[4] = {};
    const int NT = HH / 32;

    stage(0); stage(1); stage(2);
    asm volatile("s_waitcnt vmcnt(4)" ::: "memory");
    __builtin_amdgcn_s_barrier();

    for (int t = 0; t < NT; ++t) {
        const char* sA = (const char*)smem + (t & 3) * 8192;
        const char* sB = sA + 4096;

        bf16x8 af[4];
        #pragma unroll
        for (int mi = 0; mi < 4; ++mi)
            af[mi] = *(const bf16x8*)(sA + (mi * 16 + rA) * 64 + swzB);
        bf16x8 bfr = *(const bf16x8*)(sB + (w * 16 + rA) * 64 + swzB);

        if (t + 3 < NT) {
            stage(t + 3);
            asm volatile("s_waitcnt vmcnt(4)" ::: "memory");
        } else if (t + 2 < NT) {
            asm volatile("s_waitcnt vmcnt(2)" ::: "memory");
        } else {
            asm volatile("s_waitcnt vmcnt(0)" ::: "memory");
        }
        __builtin_amdgcn_s_barrier();

        __builtin_amdgcn_s_setprio(1);
        #pragma unroll
        for (int mi = 0; mi < 4; ++mi)
            acc[mi] = __builtin_amdgcn_mfma_f32_16x16x32_bf16(af[mi], bfr, acc[mi], 0, 0, 0);
        __builtin_amdgcn_s_setprio(0);
        __builtin_amdgcn_s_barrier();
    }

    const int col = w * 16 + rA;
    if (col < KA) {
        #pragma unroll
        for (int mi = 0; mi < 4; ++mi) {
            #pragma unroll
            for (int r = 0; r < 4; ++r) {
                const int rowg = bm0 + mi * 16 + ks * 4 + r;
                cs[(size_t)rowg * KA + col] = acc[mi][r];
            }
        }
    }
}

// ---------------- softz2: softmax over precomputed z + z_ext (csv = cs_partial + cg) -----
__global__ __launch_bounds__(256)
void softz2_kernel(const float* __restrict__ zb, const float* __restrict__ cg,
                   const float* __restrict__ cs, const float* __restrict__ wh,
                   float* __restrict__ alpha, float* __restrict__ beta)
{
    __shared__ float whL[64];

    const int tid = threadIdx.x;
    const int w = tid >> 6, lane = tid & 63;
    const int bt = blockIdx.x * 4 + w;

    if (tid < KA) whL[tid] = wh[tid];
    const float cgv = (lane < KA) ? cg[(size_t)bt * KA + lane] : 0.f;
    const float csv0 = (lane < KA) ? cs[(size_t)bt * KA + lane] : 0.f;
    const float z = (lane < KA) ? zb[(size_t)bt * KA + lane] : -INFINITY;
    __syncthreads();

    float u = (lane < KA) ? ftanh(csv0 + cgv) * whL[lane] : 0.f;

    float m1 = z;
    #pragma unroll
    for (int o = 32; o; o >>= 1) m1 = fmaxf(m1, __shfl_xor(m1, o, 64));
    float e = (lane < KA) ? __expf(z - m1) : 0.f;
    float s1 = e, ze = u;
    #pragma unroll
    for (int o = 32; o; o >>= 1) { s1 += __shfl_xor(s1, o, 64); ze += __shfl_xor(ze, o, 64); }

    if (lane < KA) alpha[(size_t)bt * KA + lane] = e / s1;
    if (lane == 0) {
        float M2 = fmaxf(m1, ze);
        float denom = s1 * __expf(m1 - M2) + __expf(ze - M2);
        beta[bt] = __expf(ze - M2) / denom;
    }
}

// ---------------- c = alpha@V ; ch = beta*sent + (1-beta)*c + hiddens -> bf16 ----------------
__global__ __launch_bounds__(256)
void cch_kernel(const float* __restrict__ alpha, const float* __restrict__ beta,
                const bf16* __restrict__ Vb, const bf16* __restrict__ sentb,
                const float* __restrict__ hid, bf16* __restrict__ chb)
{
    __shared__ float aL[TT * KA];
    __shared__ float bL[TT];

    const int b = blockIdx.x >> 3;
    const int hc = blockIdx.x & 7;
    const int tid = threadIdx.x;
    const int w = tid >> 6, lane = tid & 63;
    const int h = hc * 64 + lane;

    const float* ab = alpha + (size_t)b * TT * KA;
    for (int i = tid; i < TT * KA; i += 256) aL[i] = ab[i];
    if (tid < TT) bL[tid] = beta[b * TT + tid];

    float vreg[KA];
    #pragma unroll
    for (int k = 0; k < KA; ++k) vreg[k] = (float)Vb[((size_t)b * KA + k) * HH + h];
    __syncthreads();

    #pragma unroll 1
    for (int tt = 0; tt < 16; ++tt) {
        const int t = w * 16 + tt;
        const int bt = b * TT + t;
        const float* ar = aL + t * KA;
        float c = 0.f;
        #pragma unroll
        for (int k = 0; k < KA; ++k) c += ar[k] * vreg[k];
        const float be = bL[t];
        const size_t idx = (size_t)bt * HH + h;
        float ch = be * (float)sentb[idx] + (1.f - be) * c
                 + __builtin_nontemporal_load(hid + idx);
        chb[idx] = (bf16)ch;
    }
}

// ---------------- persistent 256x128 GEMM for the output projection ----------------
// R10->R11: (1) nt stores RESTORED (R10 A/B: regular stores +24 us — L2 thrash).
// (2) PERSISTENT grid: 512 blocks (2/CU), each processes 4-5 assignments of its XCD's
// chunk range (wg = xcd*316 + l + 64j). Removes inter-generation launch/dispatch gaps
// and de-phases co-resident blocks. The proven ring-3 body + transpose epilogue are
// unchanged; one added s_barrier at epilogue end (pane reads vs next assignment's
// global_load_lds into overlapping ring slots). vmcnt ledger unchanged: at the next
// prologue the issue order is [16 stores][6 loads], so vmcnt(3) => retired >= 19 =>
// stores + tile-0 loads complete (conservative, correct).
// NOTE (R7 post-mortem): do NOT widen waves to 128x64 — acc[8][4] busts the (512,4)
// VGPR cap and spills acc to scratch (measured: VGPR=64, 1.87GB fetch, MfmaUtil 3.2%).
__global__ __launch_bounds__(512, 4)
void gemm256x128_bias(const bf16* __restrict__ A, const bf16* __restrict__ B,
                      const float* __restrict__ bias, float* __restrict__ out)
{
    const int K = HH;
    const int N = NV;
    const int NT = K / 32;

    __shared__ bf16 smem[3 * 12288];

    const int bid = blockIdx.x;          // 0..511
    const int xcd = bid & 7;
    const int l0 = bid >> 3;             // 0..63

    const int tid = threadIdx.x;
    const int lane = tid & 63;
    const int wid = tid >> 6;
    const int wr = (wid >> 1) * 64;
    const int wc = (wid & 1) * 64;
    const int rA = lane & 15;
    const int ks = lane >> 4;
    const int swz = (ks ^ ((rA >> 1) & 3)) * 16;

    const int arow0 = tid >> 2;
    const int arow1 = arow0 + 128;
    const int gcA0 = ((tid & 3) ^ ((arow0 >> 1) & 3)) * 8;
    const int gcA1 = ((tid & 3) ^ ((arow1 >> 1) & 3)) * 8;
    const int brow = tid >> 2;
    const int gcB  = ((tid & 3) ^ ((brow >> 1) & 3)) * 8;

    for (int li = l0; li < 316; li += 64) {
        const int wg = xcd * 316 + li;
        const int c = wg / 320;              // chunk 0..7
        const int s = (c < 7) ? 10 : 9;      // chunk width in bn-panels
        const int loc = wg - c * 320;
        const int bm0 = (loc / s) * 256;
        const int bn0 = (10 * c + loc % s) * 128;

        const int browc = (bn0 + brow < N) ? bn0 + brow : N - 1;
        const bf16* Ap0 = A + (size_t)(bm0 + arow0) * K + gcA0;
        const bf16* Ap1 = A + (size_t)(bm0 + arow1) * K + gcA1;
        const bf16* Bp  = B + (size_t)browc * K + gcB;

        auto stage = [&](int t, int slot) {
            char* base = (char*)smem + slot * 24576;
            const int k0 = t << 5;
            __builtin_amdgcn_global_load_lds(
                (const __attribute__((address_space(1))) unsigned int*)(Ap0 + k0),
                (__attribute__((address_space(3))) unsigned int*)(base + tid * 16), 16, 0, 0);
            __builtin_amdgcn_global_load_lds(
                (const __attribute__((address_space(1))) unsigned int*)(Ap1 + k0),
                (__attribute__((address_space(3))) unsigned int*)(base + (tid + 512) * 16), 16, 0, 0);
            __builtin_amdgcn_global_load_lds(
                (const __attribute__((address_space(1))) unsigned int*)(Bp + k0),
                (__attribute__((address_space(3))) unsigned int*)(base + 16384 + tid * 16), 16, 0, 0);
        };

        f32x4 acc[4][4] = {};

        stage(0, 0); stage(1, 1);
        asm volatile("s_waitcnt vmcnt(3)" ::: "memory");
        __builtin_amdgcn_s_barrier();

        int slR = 0, slS = 2;
        for (int t = 0; t < NT; ++t) {
            const char* sA = (const char*)smem + slR * 24576;
            const char* sB = sA + 16384;

            bf16x8 af[4], bfr[4];
            #pragma unroll
            for (int mi = 0; mi < 4; ++mi)
                af[mi] = *(const bf16x8*)(sA + (wr + mi * 16 + rA) * 64 + swz);
            #pragma unroll
            for (int ni = 0; ni < 4; ++ni)
                bfr[ni] = *(const bf16x8*)(sB + (wc + ni * 16 + rA) * 64 + swz);

            if (t + 2 < NT) {
                stage(t + 2, slS);
                asm volatile("s_waitcnt vmcnt(3)" ::: "memory");
            } else {
                asm volatile("s_waitcnt vmcnt(0)" ::: "memory");
            }
            __builtin_amdgcn_s_barrier();

            __builtin_amdgcn_s_setprio(1);
            #pragma unroll
            for (int mi = 0; mi < 4; ++mi) {
                #pragma unroll
                for (int ni = 0; ni < 4; ++ni)
                    acc[mi][ni] = __builtin_amdgcn_mfma_f32_16x16x32_bf16(af[mi], bfr[ni], acc[mi][ni], 0, 0, 0);
            }
            __builtin_amdgcn_s_setprio(0);
            __builtin_amdgcn_s_barrier();

            slR = (slR == 2) ? 0 : slR + 1;
            slS = (slS == 2) ? 0 : slS + 1;
        }

        // epilogue: bias add + per-wave LDS transpose + coalesced nt dwordx4 stores
        float bv[4];
        #pragma unroll
        for (int ni = 0; ni < 4; ++ni) {
            const int col = bn0 + wc + ni * 16 + rA;
            bv[ni] = (col < N) ? bias[col] : 0.f;
        }
        float* lt = (float*)smem + wid * 2048;
        #pragma unroll
        for (int half = 0; half < 2; ++half) {
            #pragma unroll
            for (int mi2 = 0; mi2 < 2; ++mi2) {
                const int mi = half * 2 + mi2;
                #pragma unroll
                for (int ni = 0; ni < 4; ++ni) {
                    #pragma unroll
                    for (int r = 0; r < 4; ++r) {
                        const int row = mi2 * 16 + ks * 4 + r;
                        const int col = ni * 16 + rA;
                        const int s2 = ((((row >> 2) & 3) ^ (row & 3)) << 4);
                        lt[row * 64 + (col ^ s2)] = acc[mi][ni][r] + bv[ni];
                    }
                }
            }
            #pragma unroll
            for (int i = 0; i < 8; ++i) {
                const int row = i * 4 + ks;
                const int c0 = rA * 4;
                const int s2 = ((((row >> 2) & 3) ^ (row & 3)) << 4);
                f32x4 v = *(const f32x4*)&lt[row * 64 + (c0 ^ s2)];
                const int rowg = bm0 + wr + half * 32 + row;
                const int colg = bn0 + wc + c0;
                if (colg < N)
                    __builtin_nontemporal_store(v, (f32x4*)&out[(size_t)rowg * N + colg]);
            }
        }
        // pane reads (LDS) of all waves must finish before the next assignment's
        // global_load_lds lands in the overlapping ring slots.
        __builtin_amdgcn_s_barrier();
    }
}

extern "C" void kernel_launch(void* const* d_in, const int* in_sizes, int n_in,
                              void* d_out, int out_size, void* d_ws, size_t ws_size,
                              hipStream_t stream)
{
    const float* x   = (const float*)d_in[0];
    const float* hid = (const float*)d_in[1];
    const float* cel = (const float*)d_in[2];
    const float* V   = (const float*)d_in[3];
    const float* Wv  = (const float*)d_in[4];
    const float* Wg  = (const float*)d_in[5];
    const float* Ws  = (const float*)d_in[6];
    const float* wh  = (const float*)d_in[7];
    const float* Wx  = (const float*)d_in[8];
    const float* Wsh = (const float*)d_in[9];
    const float* Wm  = (const float*)d_in[10];
    const float* bm  = (const float*)d_in[11];

    float* out_o   = (float*)d_out;
    float* alpha_o = out_o + (size_t)BTT * NV;
    float* beta_o  = alpha_o + (size_t)BTT * KA;

    char* p = (char*)d_ws;
    bf16* sentb = (bf16*)p; p += (size_t)BTT * HH * 2;
    bf16* chb   = (bf16*)p; p += (size_t)BTT * HH * 2;
    bf16* hb    = (bf16*)p; p += (size_t)BTT * HH * 2;
    bf16* Vb    = (bf16*)p; p += (size_t)BB * KA * HH * 2;
    bf16* Wxb   = (bf16*)p; p += (size_t)HH * EE * 2;
    bf16* Wshb  = (bf16*)p; p += (size_t)HH * HH * 2;
    bf16* Wmb   = (bf16*)p; p += (size_t)NV * HH * 2;
    bf16* Wvb   = (bf16*)p; p += (size_t)KA * HH * 2;
    bf16* Wgb   = (bf16*)p; p += (size_t)KA * HH * 2;
    bf16* Wsb   = (bf16*)p; p += (size_t)KA * HH * 2;
    bf16* zbuf  = (bf16*)p; p += 1024 * 2;
    float* cv   = (float*)p; p += (size_t)BB * KA * KA * 4;
    float* cg   = (float*)p; p += (size_t)BTT * KA * 4;
    float* cs   = (float*)p; p += (size_t)BTT * KA * 4;
    float* zb   = (float*)p; p += (size_t)BTT * KA * 4;

    prep_kernel<<<2048, 256, 0, stream>>>(hid, V, Wv, Wg, Ws, Wx, Wsh,
                                          hb, Vb, Wvb, Wgb, Wsb, Wxb, Wshb, zbuf);

    // gate (256, direct-f32 x) + cv (49) + cg (64) + Wm-convert (143) = 512 blocks
    gate_mid128<<<512, 256, 0, stream>>>(x, Wxb, Wshb, cel, sentb,
                                         Vb, Wvb, hb, Wgb, cv, cg, Wm, Wmb, zbuf);

    // cs_partial (128 blocks, MFMA) + z precompute (2048 blocks) co-scheduled
    cs_z<<<128 + BTT / 4, 256, 0, stream>>>(sentb, Wsb, cs, cv, cg, wh, zb);

    softz2_kernel<<<BTT / 4, 256, 0, stream>>>(zb, cg, cs, wh, alpha_o, beta_o);
    cch_kernel<<<BB * 8, 256, 0, stream>>>(alpha_o, beta_o, Vb, sentb, hid, chb);

    // output = ch@Wm^T + bm   (persistent 512 blocks, ring-3, L2-chunked, nt stores)
    gemm256x128_bias<<<512, 512, 0, stream>>>(chb, Wmb, bm, out_o);
}

// Round 12
// 200.016 us; speedup vs baseline: 1.1242x; 1.1242x over previous
//
#include <hip/hip_runtime.h>
#include <hip/hip_bf16.h>
#include <math.h>

typedef __bf16 bf16;
typedef __bf16 bf16x4 __attribute__((ext_vector_type(4)));
typedef __bf16 bf16x8 __attribute__((ext_vector_type(8)));
typedef float f32x4 __attribute__((ext_vector_type(4)));

#define BB  128
#define TT  64
#define BTT 8192
#define HH  512
#define EE  1024
#define KA  49
#define NV  10000

__device__ __forceinline__ float ftanh(float x) {
    float cx = fminf(fmaxf(x, -15.f), 15.f);
    float e = __expf(2.f * cx);
    return (e - 1.f) * __builtin_amdgcn_rcpf(e + 1.f);
}
__device__ __forceinline__ float fsigmoid(float x) {
    return __builtin_amdgcn_rcpf(1.f + __expf(-x));
}

// ---------------- fused converts (one pass, float4 -> bf16x4) ----------------
__device__ __forceinline__ void cvt4(const float* __restrict__ s, bf16* __restrict__ d) {
    f32x4 v = *(const f32x4*)s;
    bf16x4 o = { (bf16)v[0], (bf16)v[1], (bf16)v[2], (bf16)v[3] };
    *(bf16x4*)d = o;
}
__device__ __forceinline__ void cvt4nt(const float* __restrict__ s, bf16* __restrict__ d) {
    f32x4 v = __builtin_nontemporal_load((const f32x4*)s);
    bf16x4 o = { (bf16)v[0], (bf16)v[1], (bf16)v[2], (bf16)v[3] };
    *(bf16x4*)d = o;
}

// x pass removed entirely (gate stages x f32 directly). Wm handled by gate_mid filler.
__global__ __launch_bounds__(256)
void prep_kernel(const float* __restrict__ hid,
                 const float* __restrict__ V, const float* __restrict__ Wv,
                 const float* __restrict__ Wg, const float* __restrict__ Ws,
                 const float* __restrict__ Wx, const float* __restrict__ Wsh,
                 bf16* __restrict__ hb,
                 bf16* __restrict__ Vb, bf16* __restrict__ Wvb, bf16* __restrict__ Wgb,
                 bf16* __restrict__ Wsb, bf16* __restrict__ Wxb, bf16* __restrict__ Wshb,
                 bf16* __restrict__ zbuf)
{
    if (blockIdx.x == 0 && threadIdx.x < 128) {
        bf16x8 z = {};
        *(bf16x8*)(zbuf + threadIdx.x * 8) = z;
    }

    const long NH = (long)BTT * HH;
    const long NVV = (long)BB * KA * HH;
    const long NWX = (long)HH * EE;
    const long NWSH = (long)HH * HH;
    const long NW = (long)KA * HH;
    const long total4 = (NH + NVV + NWX + NWSH + 3 * NW) >> 2;

    long t0 = (long)blockIdx.x * 256 + threadIdx.x;
    long st = (long)gridDim.x * 256;
    for (long i4 = t0; i4 < total4; i4 += st) {
        long i = i4 << 2;
        if (i < NH) { cvt4(hid + i, hb + i); continue; }
        i -= NH;
        if (i < NVV) { cvt4nt(V + i, Vb + i); continue; }
        i -= NVV;
        if (i < NWX) { cvt4nt(Wx + i, Wxb + i); continue; }
        i -= NWX;
        if (i < NWSH) { cvt4nt(Wsh + i, Wshb + i); continue; }
        i -= NWSH;
        if (i < NW) { cvt4nt(Wv + i, Wvb + i); continue; }
        i -= NW;
        if (i < NW) { cvt4nt(Wg + i, Wgb + i); continue; }
        i -= NW;
        cvt4nt(Ws + i, Wsb + i);
    }
}

// ---------------- pipelined 128x128 GEMM core (ring-4 BK=32, lookahead-3, counted vmcnt) ----
template<int EPI, bool SHIFT>
__device__ __forceinline__ void gemm128_core(
    bf16* smem,
    const bf16* __restrict__ A1, const bf16* __restrict__ B1, int K1,
    const bf16* __restrict__ A2, const bf16* __restrict__ B2, int K2,
    int N, const float* __restrict__ eaux, void* __restrict__ outv, int ldo,
    int bm0, int bn0, const bf16* __restrict__ zbuf)
{
    const int tid = threadIdx.x;
    const int lane = tid & 63;
    const int wid = tid >> 6;
    const int wm = (wid >> 1) * 64;
    const int wn = (wid & 1) * 64;
    const int rA = lane & 15;
    const int ks = lane >> 4;
    const int swzB = (ks ^ ((rA >> 1) & 3)) * 16;

    const int c0 = tid, c1 = tid + 256;
    const int row0 = c0 >> 2, row1 = c1 >> 2;
    const int gc0 = ((c0 & 3) ^ ((row0 >> 1) & 3)) * 8;
    const int gc1 = ((c1 & 3) ^ ((row1 >> 1) & 3)) * 8;
    const int br0 = (bn0 + row0 < N) ? bn0 + row0 : N - 1;
    const int br1 = (bn0 + row1 < N) ? bn0 + row1 : N - 1;

    const int NT1 = K1 >> 5;
    const int NT2 = K2 >> 5;
    const int NT = NT1 + NT2;

    const bf16* A1r0 = A1 + (size_t)(bm0 + row0) * K1 + gc0;
    const bf16* A1r1 = A1 + (size_t)(bm0 + row1) * K1 + gc1;
    const bf16* B1r0 = B1 + (size_t)br0 * K1 + gc0;
    const bf16* B1r1 = B1 + (size_t)br1 * K1 + gc1;
    const bf16 *A2r0 = nullptr, *A2r1 = nullptr, *B2r0 = nullptr, *B2r1 = nullptr;
    if (K2 > 0) {
        if (SHIFT) {
            A2r0 = (((bm0 + row0) & 63) == 0) ? zbuf + gc0
                                              : A2 + (size_t)(bm0 + row0 - 1) * K2 + gc0;
            A2r1 = (((bm0 + row1) & 63) == 0) ? zbuf + gc1
                                              : A2 + (size_t)(bm0 + row1 - 1) * K2 + gc1;
        } else {
            A2r0 = A2 + (size_t)(bm0 + row0) * K2 + gc0;
            A2r1 = A2 + (size_t)(bm0 + row1) * K2 + gc1;
        }
        B2r0 = B2 + (size_t)br0 * K2 + gc0;
        B2r1 = B2 + (size_t)br1 * K2 + gc1;
    }

    auto stage = [&](int t) {
        const bf16 *a0, *a1, *b0, *b1; int k0;
        if (t < NT1) { k0 = t << 5;          a0 = A1r0; a1 = A1r1; b0 = B1r0; b1 = B1r1; }
        else         { k0 = (t - NT1) << 5;  a0 = A2r0; a1 = A2r1; b0 = B2r0; b1 = B2r1; }
        char* base = (char*)smem + (t & 3) * 16384;
        __builtin_amdgcn_global_load_lds(
            (const __attribute__((address_space(1))) unsigned int*)(a0 + k0),
            (__attribute__((address_space(3))) unsigned int*)(base + c0 * 16), 16, 0, 0);
        __builtin_amdgcn_global_load_lds(
            (const __attribute__((address_space(1))) unsigned int*)(a1 + k0),
            (__attribute__((address_space(3))) unsigned int*)(base + c1 * 16), 16, 0, 0);
        __builtin_amdgcn_global_load_lds(
            (const __attribute__((address_space(1))) unsigned int*)(b0 + k0),
            (__attribute__((address_space(3))) unsigned int*)(base + 8192 + c0 * 16), 16, 0, 0);
        __builtin_amdgcn_global_load_lds(
            (const __attribute__((address_space(1))) unsigned int*)(b1 + k0),
            (__attribute__((address_space(3))) unsigned int*)(base + 8192 + c1 * 16), 16, 0, 0);
    };

    f32x4 acc[4][4] = {};

    stage(0); stage(1); stage(2);
    asm volatile("s_waitcnt vmcnt(8)" ::: "memory");
    __builtin_amdgcn_s_barrier();

    for (int t = 0; t < NT; ++t) {
        const char* sA = (const char*)smem + (t & 3) * 16384;
        const char* sB = sA + 8192;

        bf16x8 af[4], bfr[4];
        #pragma unroll
        for (int mi = 0; mi < 4; ++mi)
            af[mi] = *(const bf16x8*)(sA + (wm + mi * 16 + rA) * 64 + swzB);
        #pragma unroll
        for (int ni = 0; ni < 4; ++ni)
            bfr[ni] = *(const bf16x8*)(sB + (wn + ni * 16 + rA) * 64 + swzB);

        if (t + 3 < NT) {
            stage(t + 3);
            asm volatile("s_waitcnt vmcnt(8)" ::: "memory");
        } else if (t + 2 < NT) {
            asm volatile("s_waitcnt vmcnt(4)" ::: "memory");
        } else {
            asm volatile("s_waitcnt vmcnt(0)" ::: "memory");
        }
        __builtin_amdgcn_s_barrier();

        __builtin_amdgcn_s_setprio(1);
        #pragma unroll
        for (int mi = 0; mi < 4; ++mi) {
            #pragma unroll
            for (int ni = 0; ni < 4; ++ni)
                acc[mi][ni] = __builtin_amdgcn_mfma_f32_16x16x32_bf16(af[mi], bfr[ni], acc[mi][ni], 0, 0, 0);
        }
        __builtin_amdgcn_s_setprio(0);
        __builtin_amdgcn_s_barrier();
    }

    #pragma unroll
    for (int mi = 0; mi < 4; ++mi) {
        #pragma unroll
        for (int ni = 0; ni < 4; ++ni) {
            const int col = bn0 + wn + ni * 16 + rA;
            if (col < N) {
                #pragma unroll
                for (int r = 0; r < 4; ++r) {
                    const int rowg = bm0 + wm + mi * 16 + ks * 4 + r;
                    float v = acc[mi][ni][r];
                    if (EPI == 0) {
                        ((bf16*)outv)[(size_t)rowg * ldo + col] =
                            (bf16)(fsigmoid(v) * ftanh(eaux[(size_t)rowg * ldo + col]));
                    } else {
                        ((float*)outv)[(size_t)rowg * ldo + col] = v;
                    }
                }
            }
        }
    }
}

// ---------------- gate with direct-f32 x staging (no xb conversion pass) ----------------
__device__ __forceinline__ void gate128f(
    char* smem, const float* __restrict__ xf, const bf16* __restrict__ Wxb,
    const bf16* __restrict__ hb, const bf16* __restrict__ Wshb,
    const float* __restrict__ cel, bf16* __restrict__ sentb,
    int bm0, int bn0, const bf16* __restrict__ zbuf)
{
    const int NT1 = EE >> 5;
    const int NT = NT1 + (HH >> 5);

    const int tid = threadIdx.x;
    const int lane = tid & 63;
    const int wid = tid >> 6;
    const int wm = (wid >> 1) * 64;
    const int wn = (wid & 1) * 64;
    const int rA = lane & 15;
    const int ks = lane >> 4;
    const int swzB = (ks ^ ((rA >> 1) & 3)) * 16;

    const float* xsrc[4];
    #pragma unroll
    for (int j = 0; j < 4; ++j) {
        const int c = tid + 256 * j;
        const int row = c >> 3, slot = c & 7;
        xsrc[j] = xf + (size_t)(bm0 + row) * EE + ((slot ^ ((row >> 1) & 7)) << 2);
    }
    const int cb0 = tid, cb1 = tid + 256;
    const int brow0 = cb0 >> 2, brow1 = cb1 >> 2;
    const int gb0 = ((cb0 & 3) ^ ((brow0 >> 1) & 3)) * 8;
    const int gb1 = ((cb1 & 3) ^ ((brow1 >> 1) & 3)) * 8;

    const bf16* B1r0 = Wxb + (size_t)(bn0 + brow0) * EE + gb0;
    const bf16* B1r1 = Wxb + (size_t)(bn0 + brow1) * EE + gb1;
    const bf16* B2r0 = Wshb + (size_t)(bn0 + brow0) * HH + gb0;
    const bf16* B2r1 = Wshb + (size_t)(bn0 + brow1) * HH + gb1;
    const bf16* A2r0 = (((bm0 + brow0) & 63) == 0) ? zbuf + gb0
                                                   : hb + (size_t)(bm0 + brow0 - 1) * HH + gb0;
    const bf16* A2r1 = (((bm0 + brow1) & 63) == 0) ? zbuf + gb1
                                                   : hb + (size_t)(bm0 + brow1 - 1) * HH + gb1;

    auto stage = [&](int t, int slot) {
        char* base = smem + slot * 24576;
        if (t < NT1) {
            const int k0 = t << 5;
            #pragma unroll
            for (int j = 0; j < 4; ++j)
                __builtin_amdgcn_global_load_lds(
                    (const __attribute__((address_space(1))) unsigned int*)(xsrc[j] + k0),
                    (__attribute__((address_space(3))) unsigned int*)(base + (tid + 256 * j) * 16), 16, 0, 0);
            __builtin_amdgcn_global_load_lds(
                (const __attribute__((address_space(1))) unsigned int*)(B1r0 + k0),
                (__attribute__((address_space(3))) unsigned int*)(base + 16384 + cb0 * 16), 16, 0, 0);
            __builtin_amdgcn_global_load_lds(
                (const __attribute__((address_space(1))) unsigned int*)(B1r1 + k0),
                (__attribute__((address_space(3))) unsigned int*)(base + 16384 + cb1 * 16), 16, 0, 0);
        } else {
            const int k0 = (t - NT1) << 5;
            __builtin_amdgcn_global_load_lds(
                (const __attribute__((address_space(1))) unsigned int*)(A2r0 + k0),
                (__attribute__((address_space(3))) unsigned int*)(base + cb0 * 16), 16, 0, 0);
            __builtin_amdgcn_global_load_lds(
                (const __attribute__((address_space(1))) unsigned int*)(A2r1 + k0),
                (__attribute__((address_space(3))) unsigned int*)(base + cb1 * 16), 16, 0, 0);
            __builtin_amdgcn_global_load_lds(
                (const __attribute__((address_space(1))) unsigned int*)(B2r0 + k0),
                (__attribute__((address_space(3))) unsigned int*)(base + 16384 + cb0 * 16), 16, 0, 0);
            __builtin_amdgcn_global_load_lds(
                (const __attribute__((address_space(1))) unsigned int*)(B2r1 + k0),
                (__attribute__((address_space(3))) unsigned int*)(base + 16384 + cb1 * 16), 16, 0, 0);
        }
    };

    f32x4 acc[4][4] = {};

    stage(0, 0); stage(1, 1);
    asm volatile("s_waitcnt vmcnt(6)" ::: "memory");
    __builtin_amdgcn_s_barrier();

    int slR = 0, slS = 2;
    for (int t = 0; t < NT; ++t) {
        const char* base = smem + slR * 24576;
        const char* sB = base + 16384;

        bf16x8 af[4], bfr[4];
        if (t < NT1) {
            #pragma unroll
            for (int mi = 0; mi < 4; ++mi) {
                const int row = wm + mi * 16 + rA;
                const int m = (row >> 1) & 7;
                f32x4 lo = *(const f32x4*)(base + row * 128 + (((2 * ks) ^ m) << 4));
                f32x4 hi = *(const f32x4*)(base + row * 128 + (((2 * ks + 1) ^ m) << 4));
                bf16x8 v = { (bf16)lo[0], (bf16)lo[1], (bf16)lo[2], (bf16)lo[3],
                             (bf16)hi[0], (bf16)hi[1], (bf16)hi[2], (bf16)hi[3] };
                af[mi] = v;
            }
        } else {
            #pragma unroll
            for (int mi = 0; mi < 4; ++mi)
                af[mi] = *(const bf16x8*)(base + (wm + mi * 16 + rA) * 64 + swzB);
        }
        #pragma unroll
        for (int ni = 0; ni < 4; ++ni)
            bfr[ni] = *(const bf16x8*)(sB + (wn + ni * 16 + rA) * 64 + swzB);

        if (t + 2 < NT) {
            stage(t + 2, slS);
            if (t + 2 < NT1) asm volatile("s_waitcnt vmcnt(6)" ::: "memory");
            else             asm volatile("s_waitcnt vmcnt(4)" ::: "memory");
        } else {
            asm volatile("s_waitcnt vmcnt(0)" ::: "memory");
        }
        __builtin_amdgcn_s_barrier();

        __builtin_amdgcn_s_setprio(1);
        #pragma unroll
        for (int mi = 0; mi < 4; ++mi) {
            #pragma unroll
            for (int ni = 0; ni < 4; ++ni)
                acc[mi][ni] = __builtin_amdgcn_mfma_f32_16x16x32_bf16(af[mi], bfr[ni], acc[mi][ni], 0, 0, 0);
        }
        __builtin_amdgcn_s_setprio(0);
        __builtin_amdgcn_s_barrier();

        slR = (slR == 2) ? 0 : slR + 1;
        slS = (slS == 2) ? 0 : slS + 1;
    }

    #pragma unroll
    for (int mi = 0; mi < 4; ++mi) {
        #pragma unroll
        for (int ni = 0; ni < 4; ++ni) {
            const int col = bn0 + wn + ni * 16 + rA;
            #pragma unroll
            for (int r = 0; r < 4; ++r) {
                const int rowg = bm0 + wm + mi * 16 + ks * 4 + r;
                sentb[(size_t)rowg * HH + col] =
                    (bf16)(fsigmoid(acc[mi][ni][r]) * ftanh(cel[(size_t)rowg * HH + col]));
            }
        }
    }
}

// merged launch: gate (256) + cv (49) + cg (64) + Wm-convert filler (143) = 512 blocks.
__global__ __launch_bounds__(256, 2)
void gate_mid128(const float* __restrict__ xf, const bf16* __restrict__ Wxb,
                 const bf16* __restrict__ Wshb,
                 const float* __restrict__ cel, bf16* __restrict__ sentb,
                 const bf16* __restrict__ Vb, const bf16* __restrict__ Wvb,
                 const bf16* __restrict__ hb, const bf16* __restrict__ Wgb,
                 float* __restrict__ cv, float* __restrict__ cg,
                 const float* __restrict__ Wm, bf16* __restrict__ Wmb,
                 const bf16* __restrict__ zbuf)
{
    __shared__ char smem[73728];
    const int bid = blockIdx.x;
    if (bid >= 369) {
        const long n4 = ((long)NV * HH) >> 2;
        for (long i4 = (long)(bid - 369) * 256 + threadIdx.x; i4 < n4; i4 += 143L * 256)
            cvt4nt(Wm + (i4 << 2), Wmb + (i4 << 2));
        return;
    }
    if (bid < 256) {
        const int lin = (bid & 7) * 32 + (bid >> 3);
        gate128f(smem, xf, Wxb, hb, Wshb, cel, sentb,
                 (lin >> 2) * 128, (lin & 3) * 128, zbuf);
    } else if (bid < 305) {
        gemm128_core<2, false>((bf16*)smem, Vb, Wvb, HH, nullptr, nullptr, 0, KA, nullptr,
                               (void*)cv, KA, (bid - 256) * 128, 0, nullptr);
    } else {
        gemm128_core<2, false>((bf16*)smem, hb, Wgb, HH, nullptr, nullptr, 0, KA, nullptr,
                               (void*)cg, KA, (bid - 305) * 128, 0, nullptr);
    }
}

// ---------------- cs_z: cs64 (128 blocks) + z-precompute (2048 blocks) in one launch ------
__global__ __launch_bounds__(256, 2)
void cs_z(const bf16* __restrict__ sentb, const bf16* __restrict__ Wsb,
          float* __restrict__ cs,
          const float* __restrict__ cv, const float* __restrict__ cg,
          const float* __restrict__ wh, float* __restrict__ zb)
{
    __shared__ char sm[32768];
    const int bid = blockIdx.x;
    const int tid = threadIdx.x;

    if (bid >= 128) {
        float* cvL = (float*)sm;
        float* whL = (float*)(sm + 9604);
        float* cgL = (float*)(sm + 9860);
        const int w = tid >> 6, lane = tid & 63;
        const int bt0 = (bid - 128) * 4;
        const int b = bt0 >> 6;
        const int bt = bt0 + w;

        const float* cvb = cv + (size_t)b * KA * KA;
        for (int i = tid; i < KA * KA; i += 256) cvL[i] = cvb[i];
        if (tid < KA) whL[tid] = wh[tid];
        if (lane < KA) cgL[w * KA + lane] = cg[(size_t)bt * KA + lane];
        __syncthreads();

        if (lane < KA) {
            const float* cvk = cvL + lane * KA;
            const float* cgr = cgL + w * KA;
            float acc = 0.f;
            #pragma unroll 7
            for (int n = 0; n < KA; ++n)
                acc += ftanh(cvk[n] + cgr[n]) * whL[n];
            zb[(size_t)bt * KA + lane] = acc;
        }
        return;
    }

    bf16* smem = (bf16*)sm;
    const int bm0 = bid * 64;
    const int lane = tid & 63;
    const int w = tid >> 6;
    const int rA = lane & 15;
    const int ks = lane >> 4;
    const int swzB = (ks ^ ((rA >> 1) & 3)) * 16;

    const int row = tid >> 2;
    const int gc = ((tid & 3) ^ ((row >> 1) & 3)) * 8;
    const int browc = (row < KA) ? row : KA - 1;
    const bf16* Ar = sentb + (size_t)(bm0 + row) * HH + gc;
    const bf16* Br = Wsb + (size_t)browc * HH + gc;

    auto stage = [&](int t) {
        char* base = (char*)smem + (t & 3) * 8192;
        const int k0 = t << 5;
        __builtin_amdgcn_global_load_lds(
            (const __attribute__((address_space(1))) unsigned int*)(Ar + k0),
            (__attribute__((address_space(3))) unsigned int*)(base + tid * 16), 16, 0, 0);
        __builtin_amdgcn_global_load_lds(
            (const __attribute__((address_space(1))) unsigned int*)(Br + k0),
            (__attribute__((address_space(3))) unsigned int*)(base + 4096 + tid * 16), 16, 0, 0);
    };

    f32x4 acc[4] = {};
    const int NT = HH / 32;

    stage(0); stage(1); stage(2);
    asm volatile("s_waitcnt vmcnt(4)" ::: "memory");
    __builtin_amdgcn_s_barrier();

    for (int t = 0; t < NT; ++t) {
        const char* sA = (const char*)smem + (t & 3) * 8192;
        const char* sB = sA + 4096;

        bf16x8 af[4];
        #pragma unroll
        for (int mi = 0; mi < 4; ++mi)
            af[mi] = *(const bf16x8*)(sA + (mi * 16 + rA) * 64 + swzB);
        bf16x8 bfr = *(const bf16x8*)(sB + (w * 16 + rA) * 64 + swzB);

        if (t + 3 < NT) {
            stage(t + 3);
            asm volatile("s_waitcnt vmcnt(4)" ::: "memory");
        } else if (t + 2 < NT) {
            asm volatile("s_waitcnt vmcnt(2)" ::: "memory");
        } else {
            asm volatile("s_waitcnt vmcnt(0)" ::: "memory");
        }
        __builtin_amdgcn_s_barrier();

        __builtin_amdgcn_s_setprio(1);
        #pragma unroll
        for (int mi = 0; mi < 4; ++mi)
            acc[mi] = __builtin_amdgcn_mfma_f32_16x16x32_bf16(af[mi], bfr, acc[mi], 0, 0, 0);
        __builtin_amdgcn_s_setprio(0);
        __builtin_amdgcn_s_barrier();
    }

    const int col = w * 16 + rA;
    if (col < KA) {
        #pragma unroll
        for (int mi = 0; mi < 4; ++mi) {
            #pragma unroll
            for (int r = 0; r < 4; ++r) {
                const int rowg = bm0 + mi * 16 + ks * 4 + r;
                cs[(size_t)rowg * KA + col] = acc[mi][r];
            }
        }
    }
}

// ---------------- softz2: softmax over precomputed z + z_ext (csv = cs_partial + cg) -----
__global__ __launch_bounds__(256)
void softz2_kernel(const float* __restrict__ zb, const float* __restrict__ cg,
                   const float* __restrict__ cs, const float* __restrict__ wh,
                   float* __restrict__ alpha, float* __restrict__ beta)
{
    __shared__ float whL[64];

    const int tid = threadIdx.x;
    const int w = tid >> 6, lane = tid & 63;
    const int bt = blockIdx.x * 4 + w;

    if (tid < KA) whL[tid] = wh[tid];
    const float cgv = (lane < KA) ? cg[(size_t)bt * KA + lane] : 0.f;
    const float csv0 = (lane < KA) ? cs[(size_t)bt * KA + lane] : 0.f;
    const float z = (lane < KA) ? zb[(size_t)bt * KA + lane] : -INFINITY;
    __syncthreads();

    float u = (lane < KA) ? ftanh(csv0 + cgv) * whL[lane] : 0.f;

    float m1 = z;
    #pragma unroll
    for (int o = 32; o; o >>= 1) m1 = fmaxf(m1, __shfl_xor(m1, o, 64));
    float e = (lane < KA) ? __expf(z - m1) : 0.f;
    float s1 = e, ze = u;
    #pragma unroll
    for (int o = 32; o; o >>= 1) { s1 += __shfl_xor(s1, o, 64); ze += __shfl_xor(ze, o, 64); }

    if (lane < KA) alpha[(size_t)bt * KA + lane] = e / s1;
    if (lane == 0) {
        float M2 = fmaxf(m1, ze);
        float denom = s1 * __expf(m1 - M2) + __expf(ze - M2);
        beta[bt] = __expf(ze - M2) / denom;
    }
}

// ---------------- c = alpha@V ; ch = beta*sent + (1-beta)*c + hiddens -> bf16 ----------------
__global__ __launch_bounds__(256)
void cch_kernel(const float* __restrict__ alpha, const float* __restrict__ beta,
                const bf16* __restrict__ Vb, const bf16* __restrict__ sentb,
                const float* __restrict__ hid, bf16* __restrict__ chb)
{
    __shared__ float aL[TT * KA];
    __shared__ float bL[TT];

    const int b = blockIdx.x >> 3;
    const int hc = blockIdx.x & 7;
    const int tid = threadIdx.x;
    const int w = tid >> 6, lane = tid & 63;
    const int h = hc * 64 + lane;

    const float* ab = alpha + (size_t)b * TT * KA;
    for (int i = tid; i < TT * KA; i += 256) aL[i] = ab[i];
    if (tid < TT) bL[tid] = beta[b * TT + tid];

    float vreg[KA];
    #pragma unroll
    for (int k = 0; k < KA; ++k) vreg[k] = (float)Vb[((size_t)b * KA + k) * HH + h];
    __syncthreads();

    #pragma unroll 1
    for (int tt = 0; tt < 16; ++tt) {
        const int t = w * 16 + tt;
        const int bt = b * TT + t;
        const float* ar = aL + t * KA;
        float c = 0.f;
        #pragma unroll
        for (int k = 0; k < KA; ++k) c += ar[k] * vreg[k];
        const float be = bL[t];
        const size_t idx = (size_t)bt * HH + h;
        float ch = be * (float)sentb[idx] + (1.f - be) * c
                 + __builtin_nontemporal_load(hid + idx);
        chb[idx] = (bf16)ch;
    }
}

// ---------------- 256x128 deep-pipelined GEMM for the output projection (R9 proven) -------
// L2-chunked traversal + nt stores (R10 A/B: regular stores +24us; R11: persistent grid
// +24us — vmcnt retires in order, so the next assignment's counted wait serializes on the
// epilogue store drain. KEEP the 2528-block one-tile-per-block form).
// NOTE (R7 post-mortem): do NOT widen waves to 128x64 — acc[8][4] busts the (512,4)
// VGPR cap and spills acc to scratch (measured: VGPR=64, 1.87GB fetch, MfmaUtil 3.2%).
__global__ __launch_bounds__(512, 4)
void gemm256x128_bias(const bf16* __restrict__ A, const bf16* __restrict__ B,
                      const float* __restrict__ bias, float* __restrict__ out)
{
    const int K = HH;
    const int N = NV;
    const int NT = K / 32;

    __shared__ bf16 smem[3 * 12288];

    const int bid = blockIdx.x;
    const int wg = (bid & 7) * 316 + (bid >> 3);
    const int c = wg / 320;                 // chunk 0..7 (wg in [2240,2528) -> 7)
    const int s = (c < 7) ? 10 : 9;         // chunk width in bn-panels
    const int loc = wg - c * 320;
    const int bm0 = (loc / s) * 256;
    const int bn0 = (10 * c + loc % s) * 128;

    const int tid = threadIdx.x;
    const int lane = tid & 63;
    const int wid = tid >> 6;
    const int wr = (wid >> 1) * 64;
    const int wc = (wid & 1) * 64;
    const int rA = lane & 15;
    const int ks = lane >> 4;
    const int swz = (ks ^ ((rA >> 1) & 3)) * 16;

    const int arow0 = tid >> 2;
    const int arow1 = arow0 + 128;
    const int gcA0 = ((tid & 3) ^ ((arow0 >> 1) & 3)) * 8;
    const int gcA1 = ((tid & 3) ^ ((arow1 >> 1) & 3)) * 8;
    const int brow = tid >> 2;
    const int gcB  = ((tid & 3) ^ ((brow >> 1) & 3)) * 8;
    const int browc = (bn0 + brow < N) ? bn0 + brow : N - 1;

    const bf16* Ap0 = A + (size_t)(bm0 + arow0) * K + gcA0;
    const bf16* Ap1 = A + (size_t)(bm0 + arow1) * K + gcA1;
    const bf16* Bp  = B + (size_t)browc * K + gcB;

    auto stage = [&](int t, int slot) {
        char* base = (char*)smem + slot * 24576;
        const int k0 = t << 5;
        __builtin_amdgcn_global_load_lds(
            (const __attribute__((address_space(1))) unsigned int*)(Ap0 + k0),
            (__attribute__((address_space(3))) unsigned int*)(base + tid * 16), 16, 0, 0);
        __builtin_amdgcn_global_load_lds(
            (const __attribute__((address_space(1))) unsigned int*)(Ap1 + k0),
            (__attribute__((address_space(3))) unsigned int*)(base + (tid + 512) * 16), 16, 0, 0);
        __builtin_amdgcn_global_load_lds(
            (const __attribute__((address_space(1))) unsigned int*)(Bp + k0),
            (__attribute__((address_space(3))) unsigned int*)(base + 16384 + tid * 16), 16, 0, 0);
    };

    f32x4 acc[4][4] = {};

    stage(0, 0); stage(1, 1);
    asm volatile("s_waitcnt vmcnt(3)" ::: "memory");
    __builtin_amdgcn_s_barrier();

    int slR = 0, slS = 2;
    for (int t = 0; t < NT; ++t) {
        const char* sA = (const char*)smem + slR * 24576;
        const char* sB = sA + 16384;

        bf16x8 af[4], bfr[4];
        #pragma unroll
        for (int mi = 0; mi < 4; ++mi)
            af[mi] = *(const bf16x8*)(sA + (wr + mi * 16 + rA) * 64 + swz);
        #pragma unroll
        for (int ni = 0; ni < 4; ++ni)
            bfr[ni] = *(const bf16x8*)(sB + (wc + ni * 16 + rA) * 64 + swz);

        if (t + 2 < NT) {
            stage(t + 2, slS);
            asm volatile("s_waitcnt vmcnt(3)" ::: "memory");
        } else {
            asm volatile("s_waitcnt vmcnt(0)" ::: "memory");
        }
        __builtin_amdgcn_s_barrier();

        __builtin_amdgcn_s_setprio(1);
        #pragma unroll
        for (int mi = 0; mi < 4; ++mi) {
            #pragma unroll
            for (int ni = 0; ni < 4; ++ni)
                acc[mi][ni] = __builtin_amdgcn_mfma_f32_16x16x32_bf16(af[mi], bfr[ni], acc[mi][ni], 0, 0, 0);
        }
        __builtin_amdgcn_s_setprio(0);
        __builtin_amdgcn_s_barrier();

        slR = (slR == 2) ? 0 : slR + 1;
        slS = (slS == 2) ? 0 : slS + 1;
    }

    float bv[4];
    #pragma unroll
    for (int ni = 0; ni < 4; ++ni) {
        const int col = bn0 + wc + ni * 16 + rA;
        bv[ni] = (col < N) ? bias[col] : 0.f;
    }
    float* lt = (float*)smem + wid * 2048;
    #pragma unroll
    for (int half = 0; half < 2; ++half) {
        #pragma unroll
        for (int mi2 = 0; mi2 < 2; ++mi2) {
            const int mi = half * 2 + mi2;
            #pragma unroll
            for (int ni = 0; ni < 4; ++ni) {
                #pragma unroll
                for (int r = 0; r < 4; ++r) {
                    const int row = mi2 * 16 + ks * 4 + r;
                    const int col = ni * 16 + rA;
                    const int s2 = ((((row >> 2) & 3) ^ (row & 3)) << 4);
                    lt[row * 64 + (col ^ s2)] = acc[mi][ni][r] + bv[ni];
                }
            }
        }
        #pragma unroll
        for (int i = 0; i < 8; ++i) {
            const int row = i * 4 + ks;
            const int c0 = rA * 4;
            const int s2 = ((((row >> 2) & 3) ^ (row & 3)) << 4);
            f32x4 v = *(const f32x4*)&lt[row * 64 + (c0 ^ s2)];
            const int rowg = bm0 + wr + half * 32 + row;
            const int colg = bn0 + wc + c0;
            if (colg < N)
                __builtin_nontemporal_store(v, (f32x4*)&out[(size_t)rowg * N + colg]);
        }
    }
}

extern "C" void kernel_launch(void* const* d_in, const int* in_sizes, int n_in,
                              void* d_out, int out_size, void* d_ws, size_t ws_size,
                              hipStream_t stream)
{
    const float* x   = (const float*)d_in[0];
    const float* hid = (const float*)d_in[1];
    const float* cel = (const float*)d_in[2];
    const float* V   = (const float*)d_in[3];
    const float* Wv  = (const float*)d_in[4];
    const float* Wg  = (const float*)d_in[5];
    const float* Ws  = (const float*)d_in[6];
    const float* wh  = (const float*)d_in[7];
    const float* Wx  = (const float*)d_in[8];
    const float* Wsh = (const float*)d_in[9];
    const float* Wm  = (const float*)d_in[10];
    const float* bm  = (const float*)d_in[11];

    float* out_o   = (float*)d_out;
    float* alpha_o = out_o + (size_t)BTT * NV;
    float* beta_o  = alpha_o + (size_t)BTT * KA;

    char* p = (char*)d_ws;
    bf16* sentb = (bf16*)p; p += (size_t)BTT * HH * 2;
    bf16* chb   = (bf16*)p; p += (size_t)BTT * HH * 2;
    bf16* hb    = (bf16*)p; p += (size_t)BTT * HH * 2;
    bf16* Vb    = (bf16*)p; p += (size_t)BB * KA * HH * 2;
    bf16* Wxb   = (bf16*)p; p += (size_t)HH * EE * 2;
    bf16* Wshb  = (bf16*)p; p += (size_t)HH * HH * 2;
    bf16* Wmb   = (bf16*)p; p += (size_t)NV * HH * 2;
    bf16* Wvb   = (bf16*)p; p += (size_t)KA * HH * 2;
    bf16* Wgb   = (bf16*)p; p += (size_t)KA * HH * 2;
    bf16* Wsb   = (bf16*)p; p += (size_t)KA * HH * 2;
    bf16* zbuf  = (bf16*)p; p += 1024 * 2;
    float* cv   = (float*)p; p += (size_t)BB * KA * KA * 4;
    float* cg   = (float*)p; p += (size_t)BTT * KA * 4;
    float* cs   = (float*)p; p += (size_t)BTT * KA * 4;
    float* zb   = (float*)p; p += (size_t)BTT * KA * 4;

    prep_kernel<<<2048, 256, 0, stream>>>(hid, V, Wv, Wg, Ws, Wx, Wsh,
                                          hb, Vb, Wvb, Wgb, Wsb, Wxb, Wshb, zbuf);

    // gate (256, direct-f32 x) + cv (49) + cg (64) + Wm-convert (143) = 512 blocks
    gate_mid128<<<512, 256, 0, stream>>>(x, Wxb, Wshb, cel, sentb,
                                         Vb, Wvb, hb, Wgb, cv, cg, Wm, Wmb, zbuf);

    // cs_partial (128 blocks, MFMA) + z precompute (2048 blocks) co-scheduled
    cs_z<<<128 + BTT / 4, 256, 0, stream>>>(sentb, Wsb, cs, cv, cg, wh, zb);

    softz2_kernel<<<BTT / 4, 256, 0, stream>>>(zb, cg, cs, wh, alpha_o, beta_o);
    cch_kernel<<<BB * 8, 256, 0, stream>>>(alpha_o, beta_o, Vb, sentb, hid, chb);

    // output = ch@Wm^T + bm   (256x128 tiles, ring-3, L2-chunked traversal, nt stores)
    gemm256x128_bias<<<32 * 79, 512, 0, stream>>>(chb, Wmb, bm, out_o);
}